// Round 1
// 20218.219 us; speedup vs baseline: 1.2536x; 1.2536x over previous
//
#include <hip/hip_runtime.h>
#include <hip/hip_bf16.h>
#include <math.h>

#define L_ 6
#define D_ 1024
#define H_ 16
#define HS_ 64
#define RD_ 16
#define I_ 4096
#define V_ 50304
#define B_ 2
#define T_ 1024
#define NTOK_ 2048

typedef __bf16 bf16_t;
typedef __bf16 bf16x8 __attribute__((ext_vector_type(8)));
typedef __bf16 bf16x4 __attribute__((ext_vector_type(4)));
typedef float f32x4 __attribute__((ext_vector_type(4)));

// ---------------------------------------------------------------------------
// Embedding gather: x[tkn, :] = embed_w[ids[tkn], :]
__global__ __launch_bounds__(256) void embed_kernel(const int* __restrict__ ids,
                                                    const float* __restrict__ ew,
                                                    float* __restrict__ x) {
    int tkn = blockIdx.x;
    int tid = threadIdx.x;
    int id = ids[tkn];
    ((float4*)(x + (size_t)tkn * D_))[tid] =
        ((const float4*)(ew + (size_t)id * D_))[tid];
}

// ---------------------------------------------------------------------------
// LayerNorm: one block per token, 256 threads, float4 per thread (D=1024)
__global__ __launch_bounds__(256) void ln_kernel(const float* __restrict__ x,
                                                 const float* __restrict__ s,
                                                 const float* __restrict__ b,
                                                 float* __restrict__ out) {
    int tkn = blockIdx.x;
    int tid = threadIdx.x;
    const float4* xp = (const float4*)(x + (size_t)tkn * D_);
    float4 xv = xp[tid];
    __shared__ float red[256];
    float sum = xv.x + xv.y + xv.z + xv.w;
    red[tid] = sum;
    __syncthreads();
    for (int off = 128; off > 0; off >>= 1) {
        if (tid < off) red[tid] += red[tid + off];
        __syncthreads();
    }
    float mean = red[0] * (1.0f / (float)D_);
    __syncthreads();
    float dx0 = xv.x - mean, dx1 = xv.y - mean, dx2 = xv.z - mean, dx3 = xv.w - mean;
    red[tid] = dx0 * dx0 + dx1 * dx1 + dx2 * dx2 + dx3 * dx3;
    __syncthreads();
    for (int off = 128; off > 0; off >>= 1) {
        if (tid < off) red[tid] += red[tid + off];
        __syncthreads();
    }
    float var = red[0] * (1.0f / (float)D_);
    float r = rsqrtf(var + 1e-5f);
    int d = tid * 4;
    float4 ov;
    ov.x = dx0 * r * s[d + 0] + b[d + 0];
    ov.y = dx1 * r * s[d + 1] + b[d + 1];
    ov.z = dx2 * r * s[d + 2] + b[d + 2];
    ov.w = dx3 * r * s[d + 3] + b[d + 3];
    ((float4*)(out + (size_t)tkn * D_))[tid] = ov;
}

// ---------------------------------------------------------------------------
// Legacy fp32 VALU GEMM (fallback when workspace is too small for MFMA path)
#define BM 64
#define BN 64
#define BK 16
__global__ __launch_bounds__(256) void gemm_kernel(
    const float* __restrict__ A, const float* __restrict__ W,
    const float* __restrict__ bias, const float* __restrict__ add1,
    const float* __restrict__ add2, float* __restrict__ C,
    int M, int N, int K, int act) {
    __shared__ float As[BK][BM];
    __shared__ float Bs[BK][BN];
    int tid = threadIdx.x;
    int m0 = blockIdx.y * BM, n0 = blockIdx.x * BN;
    int tx = tid & 15, ty = tid >> 4;
    float acc[4][4] = {};
    int lm = tid >> 2;
    int lk4 = (tid & 3) * 4;
    int lkb = tid >> 4;
    int lnb = (tid & 15) * 4;
    for (int k0 = 0; k0 < K; k0 += BK) {
        float4 av = *(const float4*)(A + (size_t)(m0 + lm) * K + k0 + lk4);
        As[lk4 + 0][lm] = av.x;
        As[lk4 + 1][lm] = av.y;
        As[lk4 + 2][lm] = av.z;
        As[lk4 + 3][lm] = av.w;
        *(float4*)&Bs[lkb][lnb] =
            *(const float4*)(W + (size_t)(k0 + lkb) * N + n0 + lnb);
        __syncthreads();
#pragma unroll
        for (int kk = 0; kk < BK; ++kk) {
            float a[4], bb[4];
#pragma unroll
            for (int i = 0; i < 4; ++i) a[i] = As[kk][ty * 4 + i];
#pragma unroll
            for (int j = 0; j < 4; ++j) bb[j] = Bs[kk][tx * 4 + j];
#pragma unroll
            for (int i = 0; i < 4; ++i)
#pragma unroll
                for (int j = 0; j < 4; ++j) acc[i][j] += a[i] * bb[j];
        }
        __syncthreads();
    }
#pragma unroll
    for (int i = 0; i < 4; ++i) {
        int m = m0 + ty * 4 + i;
#pragma unroll
        for (int j = 0; j < 4; ++j) {
            int n = n0 + tx * 4 + j;
            float v = acc[i][j];
            if (bias) v += bias[n];
            if (act == 1) v = 0.5f * v * (1.0f + erff(v * 0.70710678118654752f));
            size_t idx = (size_t)m * N + n;
            if (add1) v += add1[idx];
            if (add2) v += add2[idx];
            C[idx] = v;
        }
    }
}

// ---------------------------------------------------------------------------
// Split fp32 activation A[M*K] into bf16 hi/lo planes (one float4 per thread)
__global__ __launch_bounds__(256) void asplit_kernel(const float* __restrict__ A,
                                                     bf16_t* __restrict__ hi,
                                                     bf16_t* __restrict__ lo) {
    int i = blockIdx.x * 256 + threadIdx.x;
    float4 v = ((const float4*)A)[i];
    float f0 = v.x, f1 = v.y, f2 = v.z, f3 = v.w;
    bf16x4 h, l;
    bf16_t h0 = (bf16_t)f0; h[0] = h0; l[0] = (bf16_t)(f0 - (float)h0);
    bf16_t h1 = (bf16_t)f1; h[1] = h1; l[1] = (bf16_t)(f1 - (float)h1);
    bf16_t h2 = (bf16_t)f2; h[2] = h2; l[2] = (bf16_t)(f2 - (float)h2);
    bf16_t h3 = (bf16_t)f3; h[3] = h3; l[3] = (bf16_t)(f3 - (float)h3);
    ((bf16x4*)hi)[i] = h;
    ((bf16x4*)lo)[i] = l;
}

// ---------------------------------------------------------------------------
// Transpose + split weights: W[K][N] fp32 -> th/tl[(n-c0)][K] bf16 (cols c0..)
__global__ __launch_bounds__(256) void tsplit_kernel(const float* __restrict__ W,
                                                     bf16_t* __restrict__ th,
                                                     bf16_t* __restrict__ tl,
                                                     int K, int N, int c0) {
    __shared__ float tile[32][33];
    int k0 = blockIdx.y * 32;
    int nloc = blockIdx.x * 32;
    int tid = threadIdx.x;
    int r = tid >> 3;          // 0..31
    int c4 = (tid & 7) * 4;    // 0..28
    float4 v = *(const float4*)(W + (size_t)(k0 + r) * N + c0 + nloc + c4);
    tile[r][c4 + 0] = v.x;
    tile[r][c4 + 1] = v.y;
    tile[r][c4 + 2] = v.z;
    tile[r][c4 + 3] = v.w;
    __syncthreads();
    bf16x4 h, l;
#pragma unroll
    for (int j = 0; j < 4; ++j) {
        float x = tile[c4 + j][r];
        bf16_t hh = (bf16_t)x;
        h[j] = hh;
        l[j] = (bf16_t)(x - (float)hh);
    }
    size_t obase = (size_t)(nloc + r) * K + k0 + c4;
    *(bf16x4*)(th + obase) = h;
    *(bf16x4*)(tl + obase) = l;
}

// ---------------------------------------------------------------------------
// Split-bf16 MFMA GEMM: C = act(A@W + bias) + add1 + add2
// A given as bf16 hi/lo [M][K]; W given as transposed bf16 hi/lo [N][K].
// A@W ~= Ah@Wh + Ah@Wl + Al@Wh (fp32 accum). Tile 128x128, BK=32, 4 waves.
__global__ __launch_bounds__(256) void mgemm_kernel(
    const bf16_t* __restrict__ Ah, const bf16_t* __restrict__ Al,
    const bf16_t* __restrict__ Bh, const bf16_t* __restrict__ Bl,
    const float* __restrict__ bias, const float* __restrict__ add1,
    const float* __restrict__ add2, float* __restrict__ C,
    int K, int ldc, int act) {
    __shared__ bf16_t sAh[128 * 32];
    __shared__ bf16_t sAl[128 * 32];
    __shared__ bf16_t sBh[128 * 32];
    __shared__ bf16_t sBl[128 * 32];
    int tid = threadIdx.x;
    int m0 = blockIdx.x * 128;
    int n0 = blockIdx.y * 128;
    int lane = tid & 63;
    int wid = tid >> 6;
    int wr = wid >> 1, wc = wid & 1;
    int srow = tid >> 2;        // 0..63 (row within tile, +64 for s=1)
    int sq = (tid & 3) * 8;     // k-chunk (8 bf16 = 16B)

    bf16x8 st[8];
#define LOADT(k0_)                                                              \
    do {                                                                        \
        _Pragma("unroll") for (int s = 0; s < 2; ++s) {                         \
            int rr = srow + 64 * s;                                             \
            st[s * 4 + 0] = *(const bf16x8*)(Ah + (size_t)(m0 + rr) * K + (k0_) + sq); \
            st[s * 4 + 1] = *(const bf16x8*)(Al + (size_t)(m0 + rr) * K + (k0_) + sq); \
            st[s * 4 + 2] = *(const bf16x8*)(Bh + (size_t)(n0 + rr) * K + (k0_) + sq); \
            st[s * 4 + 3] = *(const bf16x8*)(Bl + (size_t)(n0 + rr) * K + (k0_) + sq); \
        }                                                                       \
    } while (0)

#define STORET()                                                                \
    do {                                                                        \
        _Pragma("unroll") for (int s = 0; s < 2; ++s) {                         \
            int rr = srow + 64 * s;                                             \
            *(bf16x8*)&sAh[rr * 32 + sq] = st[s * 4 + 0];                       \
            *(bf16x8*)&sAl[rr * 32 + sq] = st[s * 4 + 1];                       \
            *(bf16x8*)&sBh[rr * 32 + sq] = st[s * 4 + 2];                       \
            *(bf16x8*)&sBl[rr * 32 + sq] = st[s * 4 + 3];                       \
        }                                                                       \
    } while (0)

    f32x4 acc[4][4] = {};
    int nk = K >> 5;
    int lr = lane & 15;
    int lq = (lane >> 4) * 8;
    LOADT(0);
    for (int kt = 0; kt < nk; ++kt) {
        __syncthreads();
        STORET();
        __syncthreads();
        if (kt + 1 < nk) LOADT((kt + 1) << 5);
        bf16x8 fa[4], fal[4], fb[4], fbl[4];
#pragma unroll
        for (int i = 0; i < 4; ++i) {
            int ra = (wr * 64 + i * 16 + lr) * 32 + lq;
            fa[i] = *(const bf16x8*)&sAh[ra];
            fal[i] = *(const bf16x8*)&sAl[ra];
            int rb = (wc * 64 + i * 16 + lr) * 32 + lq;
            fb[i] = *(const bf16x8*)&sBh[rb];
            fbl[i] = *(const bf16x8*)&sBl[rb];
        }
#pragma unroll
        for (int i = 0; i < 4; ++i)
#pragma unroll
            for (int j = 0; j < 4; ++j) {
                acc[i][j] = __builtin_amdgcn_mfma_f32_16x16x32_bf16(
                    fa[i], fb[j], acc[i][j], 0, 0, 0);
                acc[i][j] = __builtin_amdgcn_mfma_f32_16x16x32_bf16(
                    fa[i], fbl[j], acc[i][j], 0, 0, 0);
                acc[i][j] = __builtin_amdgcn_mfma_f32_16x16x32_bf16(
                    fal[i], fb[j], acc[i][j], 0, 0, 0);
            }
    }
#undef LOADT
#undef STORET
    // Epilogue. C/D layout (verified m89/m91): col=lane&15, row=(lane>>4)*4+r
#pragma unroll
    for (int i = 0; i < 4; ++i) {
#pragma unroll
        for (int j = 0; j < 4; ++j) {
            int row = m0 + wr * 64 + i * 16 + ((lane >> 4) << 2);
            int col = n0 + wc * 64 + j * 16 + lr;
            float bv = bias ? bias[col] : 0.0f;
#pragma unroll
            for (int r = 0; r < 4; ++r) {
                float v = acc[i][j][r] + bv;
                if (act == 1) v = 0.5f * v * (1.0f + erff(v * 0.70710678118654752f));
                size_t idx = (size_t)(row + r) * ldc + col;
                if (add1) v += add1[idx];
                if (add2) v += add2[idx];
                C[idx] = v;
            }
        }
    }
}

// ---------------------------------------------------------------------------
// QKV split + RoPE scatter.
__global__ __launch_bounds__(64) void rope_scatter_kernel(
    const float* __restrict__ qkv, float* __restrict__ q,
    float* __restrict__ k, float* __restrict__ v) {
    int tkn = blockIdx.x;
    int h = blockIdx.y;
    int d = threadIdx.x;
    int b = tkn >> 10;
    int t = tkn & 1023;
    __shared__ float qs[HS_], ks[HS_];
    const float* base = qkv + (size_t)tkn * (3 * D_) + h * (3 * HS_);
    float qv = base[d];
    float kv = base[HS_ + d];
    float vv = base[2 * HS_ + d];
    qs[d] = qv;
    ks[d] = kv;
    __syncthreads();
    if (d < RD_) {
        int i = d & 7;
        float inv = powf(10000.0f, -(float)(2 * i) / (float)RD_);
        float ang = (float)t * inv;
        float c = cosf(ang), s = sinf(ang);
        float qr = (d < 8) ? -qs[d + 8] : qs[d - 8];
        float kr = (d < 8) ? -ks[d + 8] : ks[d - 8];
        qv = qv * c + qr * s;
        kv = kv * c + kr * s;
    }
    size_t out_idx = ((size_t)(b * H_ + h) * T_ + t) * HS_ + d;
    q[out_idx] = qv;
    k[out_idx] = kv;
    v[out_idx] = vv;
}

// ---------------------------------------------------------------------------
// Attention: one block per (query row, b*h).
__global__ __launch_bounds__(256) void attn_kernel(const float* __restrict__ q,
                                                   const float* __restrict__ k,
                                                   const float* __restrict__ v,
                                                   float* __restrict__ att2) {
    int tq = blockIdx.x;
    int bh = blockIdx.y;
    int b = bh >> 4, h = bh & 15;
    int tid = threadIdx.x;
    __shared__ float qs[HS_];
    __shared__ float sc[T_];
    __shared__ float red[256];
    const float* qp = q + ((size_t)bh * T_ + tq) * HS_;
    if (tid < HS_) qs[tid] = qp[tid];
    __syncthreads();
    float svals[4];
    float lmax = -1e30f;
#pragma unroll
    for (int jj = 0; jj < 4; ++jj) {
        int j = jj * 256 + tid;
        const float4* kp = (const float4*)(k + ((size_t)bh * T_ + j) * HS_);
        float s = 0.0f;
#pragma unroll
        for (int d4 = 0; d4 < 16; ++d4) {
            float4 kv = kp[d4];
            s += qs[d4 * 4 + 0] * kv.x + qs[d4 * 4 + 1] * kv.y +
                 qs[d4 * 4 + 2] * kv.z + qs[d4 * 4 + 3] * kv.w;
        }
        s = s * 0.125f + (j > tq ? -10000.0f : 0.0f);
        svals[jj] = s;
        lmax = fmaxf(lmax, s);
    }
    red[tid] = lmax;
    __syncthreads();
    for (int off = 128; off > 0; off >>= 1) {
        if (tid < off) red[tid] = fmaxf(red[tid], red[tid + off]);
        __syncthreads();
    }
    float mx = red[0];
    __syncthreads();
    float lsum = 0.0f;
#pragma unroll
    for (int jj = 0; jj < 4; ++jj) {
        int j = jj * 256 + tid;
        float e = expf(svals[jj] - mx);
        sc[j] = e;
        lsum += e;
    }
    red[tid] = lsum;
    __syncthreads();
    for (int off = 128; off > 0; off >>= 1) {
        if (tid < off) red[tid] += red[tid + off];
        __syncthreads();
    }
    float inv = 1.0f / red[0];
    __syncthreads();
    int d = tid & 63;
    int part = tid >> 6;
    float acc = 0.0f;
    const float* vp = v + (size_t)bh * T_ * HS_;
    for (int j = part * 256; j < part * 256 + 256; ++j)
        acc += sc[j] * vp[(size_t)j * HS_ + d];
    red[tid] = acc;
    __syncthreads();
    if (tid < 64) {
        float o = (red[tid] + red[64 + tid] + red[128 + tid] + red[192 + tid]) * inv;
        att2[((size_t)(b * T_ + tq)) * D_ + h * HS_ + tid] = o;
    }
}

// ---------------------------------------------------------------------------
static void run_mgemm(const float* A, const float* W, const float* bias,
                      const float* add1, const float* add2, float* Cp,
                      int M, int N, int K, int act,
                      bf16_t* a_hi, bf16_t* a_lo, bf16_t* wt_hi, bf16_t* wt_lo,
                      hipStream_t stream) {
    asplit_kernel<<<(M * K) / 1024, 256, 0, stream>>>(A, a_hi, a_lo);
    for (int c0 = 0; c0 < N; c0 += 8192) {
        int clen = (N - c0 > 8192) ? 8192 : (N - c0);
        tsplit_kernel<<<dim3(clen / 32, K / 32), 256, 0, stream>>>(
            W, wt_hi, wt_lo, K, N, c0);
        // m-index fastest (blockIdx.x) -> the 16 m-blocks of one W panel run
        // adjacently and share the panel in L2.
        mgemm_kernel<<<dim3(M / 128, clen / 128), 256, 0, stream>>>(
            a_hi, a_lo, wt_hi, wt_lo, bias ? bias + c0 : nullptr,
            add1 ? add1 + c0 : nullptr, add2 ? add2 + c0 : nullptr, Cp + c0,
            K, N, act);
    }
}

extern "C" void kernel_launch(void* const* d_in, const int* in_sizes, int n_in,
                              void* d_out, int out_size, void* d_ws, size_t ws_size,
                              hipStream_t stream) {
    const int*   ids     = (const int*)d_in[0];
    const float* embed_w = (const float*)d_in[1];
    const float* ln1_s   = (const float*)d_in[2];
    const float* ln1_b   = (const float*)d_in[3];
    const float* ln2_s   = (const float*)d_in[4];
    const float* ln2_b   = (const float*)d_in[5];
    const float* qkv_w   = (const float*)d_in[6];
    const float* qkv_b   = (const float*)d_in[7];
    const float* dense_w = (const float*)d_in[8];
    const float* dense_b = (const float*)d_in[9];
    const float* fc1_w   = (const float*)d_in[10];
    const float* fc1_b   = (const float*)d_in[11];
    const float* fc2_w   = (const float*)d_in[12];
    const float* fc2_b   = (const float*)d_in[13];
    const float* fln_s   = (const float*)d_in[14];
    const float* fln_b   = (const float*)d_in[15];
    const float* head_w  = (const float*)d_in[16];
    float* out = (float*)d_out;

    const size_t TD = (size_t)NTOK_ * D_;   // 2M floats
    float* ws = (float*)d_ws;
    float* x    = ws;             // TD
    float* h    = x + TD;         // TD
    float* qkv  = h + TD;         // 3*TD
    float* qb   = qkv + 3 * TD;   // TD
    float* kb   = qb + TD;        // TD
    float* vb   = kb + TD;        // TD
    float* att2 = vb + TD;        // TD
    float* attp = att2 + TD;      // TD
    float* mlp1 = attp + TD;      // NTOK*I = 4*TD

    // MFMA-path scratch (after the 12*TD fp32 region):
    // a_hi/a_lo: split activations (max 2048x4096 elems)
    // wt_hi/wt_lo: transposed+split weight panel (max 8192x1024 elems)
    const size_t SPLIT_ELEMS = 8388608;  // 8192*1024
    bf16_t* a_hi  = (bf16_t*)(mlp1 + 4 * TD);
    bf16_t* a_lo  = a_hi + SPLIT_ELEMS;
    bf16_t* wt_hi = a_lo + SPLIT_ELEMS;
    bf16_t* wt_lo = wt_hi + SPLIT_ELEMS;
    const size_t NEED = 12 * TD * sizeof(float) + 4 * SPLIT_ELEMS * sizeof(bf16_t);
    const bool mfma_ok = (ws_size >= NEED);

    // Embedding
    embed_kernel<<<NTOK_, 256, 0, stream>>>(ids, embed_w, x);

    for (int l = 0; l < L_; ++l) {
        const float* l1s = ln1_s + (size_t)l * D_;
        const float* l1b = ln1_b + (size_t)l * D_;
        const float* l2s = ln2_s + (size_t)l * D_;
        const float* l2b = ln2_b + (size_t)l * D_;
        const float* qw  = qkv_w + (size_t)l * D_ * 3 * D_;
        const float* qbi = qkv_b + (size_t)l * 3 * D_;
        const float* dw  = dense_w + (size_t)l * D_ * D_;
        const float* dbi = dense_b + (size_t)l * D_;
        const float* f1w = fc1_w + (size_t)l * D_ * I_;
        const float* f1b = fc1_b + (size_t)l * I_;
        const float* f2w = fc2_w + (size_t)l * I_ * D_;
        const float* f2b = fc2_b + (size_t)l * D_;

        // h = ln1(x)
        ln_kernel<<<NTOK_, 256, 0, stream>>>(x, l1s, l1b, h);
        // qkv = h @ qw + qb
        if (mfma_ok)
            run_mgemm(h, qw, qbi, nullptr, nullptr, qkv, NTOK_, 3 * D_, D_, 0,
                      a_hi, a_lo, wt_hi, wt_lo, stream);
        else
            gemm_kernel<<<dim3(3 * D_ / BN, NTOK_ / BM), 256, 0, stream>>>(
                h, qw, qbi, nullptr, nullptr, qkv, NTOK_, 3 * D_, D_, 0);
        // split + rope
        rope_scatter_kernel<<<dim3(NTOK_, H_), 64, 0, stream>>>(qkv, qb, kb, vb);
        // attention
        attn_kernel<<<dim3(T_, B_ * H_), 256, 0, stream>>>(qb, kb, vb, att2);
        // attp = att2 @ dw + dbi
        if (mfma_ok)
            run_mgemm(att2, dw, dbi, nullptr, nullptr, attp, NTOK_, D_, D_, 0,
                      a_hi, a_lo, wt_hi, wt_lo, stream);
        else
            gemm_kernel<<<dim3(D_ / BN, NTOK_ / BM), 256, 0, stream>>>(
                att2, dw, dbi, nullptr, nullptr, attp, NTOK_, D_, D_, 0);
        // h = ln2(x)
        ln_kernel<<<NTOK_, 256, 0, stream>>>(x, l2s, l2b, h);
        // mlp1 = gelu(h @ f1w + f1b)
        if (mfma_ok)
            run_mgemm(h, f1w, f1b, nullptr, nullptr, mlp1, NTOK_, I_, D_, 1,
                      a_hi, a_lo, wt_hi, wt_lo, stream);
        else
            gemm_kernel<<<dim3(I_ / BN, NTOK_ / BM), 256, 0, stream>>>(
                h, f1w, f1b, nullptr, nullptr, mlp1, NTOK_, I_, D_, 1);
        // x = mlp1 @ f2w + f2b + attp + x
        if (mfma_ok)
            run_mgemm(mlp1, f2w, f2b, attp, x, x, NTOK_, D_, I_, 0,
                      a_hi, a_lo, wt_hi, wt_lo, stream);
        else
            gemm_kernel<<<dim3(D_ / BN, NTOK_ / BM), 256, 0, stream>>>(
                mlp1, f2w, f2b, attp, x, x, NTOK_, D_, I_, 0);
    }

    // final ln + head
    ln_kernel<<<NTOK_, 256, 0, stream>>>(x, fln_s, fln_b, h);
    if (mfma_ok)
        run_mgemm(h, head_w, nullptr, nullptr, nullptr, out, NTOK_, V_, D_, 0,
                  a_hi, a_lo, wt_hi, wt_lo, stream);
    else
        gemm_kernel<<<dim3(V_ / BN, NTOK_ / BM), 256, 0, stream>>>(
            h, head_w, nullptr, nullptr, nullptr, out, NTOK_, V_, D_, 0);
}